// Round 7
// baseline (316.054 us; speedup 1.0000x reference)
//
#include <hip/hip_runtime.h>
#include <math.h>

#define BB 8
#define CC 256
#define NN 4096

typedef float f4 __attribute__((ext_vector_type(4)));
typedef short bh8 __attribute__((ext_vector_type(8)));

__device__ __forceinline__ unsigned short f2bf(float f) {
    unsigned u = __builtin_bit_cast(unsigned, f);
    u += 0x7fff + ((u >> 16) & 1);
    return (unsigned short)(u >> 16);
}

// ---------------------------------------------------------------------------
// Kernel 0: concatenate weights into WcatT[c][320] + bcat[320] (fp32).
// ---------------------------------------------------------------------------
__global__ void prep_w_kernel(const float* __restrict__ Wq, const float* __restrict__ bq,
                              const float* __restrict__ Wk, const float* __restrict__ bk,
                              const float* __restrict__ Wv, const float* __restrict__ bv,
                              float* __restrict__ WcatT, float* __restrict__ bcat) {
    int idx = blockIdx.x * 256 + threadIdx.x;
    if (idx < 320) {
        bcat[idx] = (idx < 32) ? bq[idx] : (idx < 64 ? bk[idx - 32] : bv[idx - 64]);
    }
    if (idx < 320 * 256) {
        int o = idx >> 8;
        int c = idx & 255;
        float v = (o < 32) ? Wq[o * 256 + c]
                           : (o < 64 ? Wk[(o - 32) * 256 + c] : Wv[(o - 64) * 256 + c]);
        WcatT[c * 320 + o] = v;
    }
}

// ---------------------------------------------------------------------------
// Kernel 1: QKV projection (fp32 math), bf16 outputs.
// Position remap ii = 16*tp + pi: x reads become 4 broadcast ds_read_b128
// per channel (was 16 scalar ds_read_b32).
// ---------------------------------------------------------------------------
__global__ __launch_bounds__(256, 2) void qkv_kernel(
    const float* __restrict__ x, const float* __restrict__ WcatT,
    const float* __restrict__ bcat,
    unsigned short* __restrict__ q64, unsigned short* __restrict__ k64,
    unsigned short* __restrict__ vC) {
    __shared__ float xs[256 * 64];
    __shared__ unsigned short qkl[64 * 128];
    unsigned short* vsl = (unsigned short*)xs;  // [256][66] u16 overlay

    int blk = blockIdx.x;
    int b = blk >> 6;
    int i0 = (blk & 63) << 6;
    int t = threadIdx.x;

    const float* xb = x + ((size_t)b << 20);
    for (int idx = t; idx < 256 * 64; idx += 256) {
        int c = idx >> 6, ii = idx & 63;
        xs[idx] = xb[((size_t)c << 12) + i0 + ii];
    }
    __syncthreads();

    int to = t & 63;
    int tp = t >> 6;  // wave-uniform

    float acc[80];
#pragma unroll
    for (int uo = 0; uo < 5; ++uo) {
        float bias = bcat[to + 64 * uo];
#pragma unroll
        for (int pi = 0; pi < 16; ++pi) acc[uo * 16 + pi] = bias;
    }

    for (int c = 0; c < 256; ++c) {
        const float* wc = WcatT + c * 320 + to;
        float w0 = wc[0];
        float w1 = wc[64];
        float w2 = wc[128];
        float w3 = wc[192];
        float w4 = wc[256];
        const float4* xr = (const float4*)(xs + c * 64 + 16 * tp);
#pragma unroll
        for (int q = 0; q < 4; ++q) {
            float4 xv = xr[q];  // broadcast (wave-uniform address)
#pragma unroll
            for (int e = 0; e < 4; ++e) {
                int pi = 4 * q + e;
                float xe = (e == 0) ? xv.x : (e == 1) ? xv.y : (e == 2) ? xv.z : xv.w;
                acc[0 * 16 + pi] += w0 * xe;
                acc[1 * 16 + pi] += w1 * xe;
                acc[2 * 16 + pi] += w2 * xe;
                acc[3 * 16 + pi] += w3 * xe;
                acc[4 * 16 + pi] += w4 * xe;
            }
        }
    }
    __syncthreads();

#pragma unroll
    for (int pi = 0; pi < 16; ++pi) {
        int ii = 16 * tp + pi;
        float v = acc[pi];  // uo == 0
        unsigned short hi = f2bf(v);
        float vhi = __builtin_bit_cast(float, ((unsigned)hi) << 16);
        unsigned short lo = f2bf(v - vhi);
        if (to < 32) {
            qkl[ii * 128 + to] = hi;
            qkl[ii * 128 + 32 + to] = lo;
        } else {
            qkl[ii * 128 + 32 + to] = hi;
            qkl[ii * 128 + 64 + to] = lo;
        }
    }
#pragma unroll
    for (int uo = 1; uo < 5; ++uo) {
#pragma unroll
        for (int pi = 0; pi < 16; ++pi) {
            int c = to + 64 * (uo - 1);
            int ii = 16 * tp + pi;
            vsl[c * 66 + ii] = f2bf(acc[uo * 16 + pi]);
        }
    }
    __syncthreads();

    const unsigned* qk32 = (const unsigned*)qkl;
    unsigned* qb = (unsigned*)(q64 + ((size_t)(b * NN + i0)) * 64);
    unsigned* kb = (unsigned*)(k64 + ((size_t)(b * NN + i0)) * 64);
    for (int idx = t; idx < 64 * 32; idx += 256) {
        int row = idx >> 5, dw = idx & 31;
        qb[row * 32 + dw] = qk32[row * 64 + dw];
        kb[row * 32 + dw] = qk32[row * 64 + 32 + dw];
    }
    for (int idx = t; idx < 256 * 32; idx += 256) {
        int c = idx >> 5, dw = idx & 31;
        unsigned val = *(const unsigned*)(vsl + c * 66 + 2 * dw);
        *(unsigned*)(vC + ((size_t)(b * CC + c)) * NN + i0 + 2 * dw) = val;
    }
}

// ---------------------------------------------------------------------------
// Kernel 2: MFMA flash attention + residual. Pipelined + V-register prefetch.
// Grid 512 (8 b x 64 q-tiles), 4 waves x 16 queries, 2 blocks/CU.
// Pipeline: QK[t+1] issued adjacent to softmax[t]; PV in 4 groups of 8 with
// group-0 V ds_reads issued at step TOP (hidden under QK+softmax) and each
// later group's reads issued under the previous group's MFMAs.
// Defer-max (THR=8). V channel-major [256][64] bf16 LDS, XOR-swizzled,
// double-buffered via global_load_lds.
// ---------------------------------------------------------------------------
__global__ __launch_bounds__(256, 2) void attn_kernel(
    const unsigned short* __restrict__ q64, const unsigned short* __restrict__ k64,
    const unsigned short* __restrict__ vC, const float* __restrict__ x,
    const float* __restrict__ gamma, float* __restrict__ out) {
    __shared__ unsigned short vs[2][256 * 64];  // 64KB double-buffered V

    int t = threadIdx.x;
    int lane = t & 63;
    int w = t >> 6;
    int g = lane >> 4;
    int li = lane & 15;
    int blk = blockIdx.x;
    int b = blk & 7;            // XCD-affine batch mapping
    int i0 = (blk >> 3) << 6;   // 64-query tile
    int qb = i0 + 16 * w;       // wave's query base (16 queries)

    const unsigned short* vb = vC + ((size_t)b * CC) * NN;
    const unsigned short* kb = k64 + ((size_t)b * NN) * 64;

    // Q fragments (resident): [hi/lo]
    bh8 qf[2];
#pragma unroll
    for (int s = 0; s < 2; ++s)
        qf[s] = *(const bh8*)(q64 + ((size_t)(b * NN + qb + li)) * 64 + s * 32 + 8 * g);

    f4 acc[16];
#pragma unroll
    for (int ct = 0; ct < 16; ++ct) acc[ct] = (f4){0.f, 0.f, 0.f, 0.f};
    float m = -INFINITY, l = 0.f;

    auto stageV = [&](int buf, int j0) {
#pragma unroll
        for (int s = 0; s < 8; ++s) {
            int c = 64 * w + 8 * s + (lane >> 3);
            int slot = (lane & 7) ^ (c & 7);
            const unsigned short* src = vb + (size_t)c * NN + j0 + slot * 8;
            __builtin_amdgcn_global_load_lds(
                (const __attribute__((address_space(1))) unsigned int*)src,
                (__attribute__((address_space(3))) unsigned int*)(&vs[buf][(64 * w + 8 * s) * 64]),
                16, 0, 0);
        }
    };
    auto loadK = [&](bh8 (&kf)[4][2], int j0) {
#pragma unroll
        for (int jt = 0; jt < 4; ++jt)
#pragma unroll
            for (int s = 0; s < 2; ++s)
                kf[jt][s] = *(const bh8*)(kb + (size_t)(j0 + 16 * jt + li) * 64 + s * 32 + 8 * g);
    };
    // QK^T (swapped, 3-product bf16 split => ~fp32 scores)
    auto qkComp = [&](f4 (&sOut)[4], bh8 (&kc)[4][2]) {
#pragma unroll
        for (int jt = 0; jt < 4; ++jt) {
            f4 a = {0.f, 0.f, 0.f, 0.f};
            a = __builtin_amdgcn_mfma_f32_16x16x32_bf16(kc[jt][0], qf[0], a, 0, 0, 0);
            a = __builtin_amdgcn_mfma_f32_16x16x32_bf16(kc[jt][1], qf[0], a, 0, 0, 0);
            a = __builtin_amdgcn_mfma_f32_16x16x32_bf16(kc[jt][0], qf[1], a, 0, 0, 0);
            sOut[jt] = a;
        }
    };
    // P^T fragment for k-half h via shfl redistribution (proven numerics)
    auto mkpb = [&](f4 (&sCur)[4], int h) -> bh8 {
        unsigned pk[2][2];
#pragma unroll
        for (int tl = 0; tl < 2; ++tl)
#pragma unroll
            for (int pp = 0; pp < 2; ++pp) {
                unsigned lo16 = f2bf(sCur[2 * h + tl][2 * pp]);
                unsigned hi16 = f2bf(sCur[2 * h + tl][2 * pp + 1]);
                pk[tl][pp] = lo16 | (hi16 << 16);
            }
        union { unsigned u[4]; bh8 v; } un;
#pragma unroll
        for (int d = 0; d < 4; ++d) {
            int srcl = (((2 * g + (d >> 1)) & 3) << 4) | li;
            unsigned a0 = (unsigned)__shfl((int)pk[0][d & 1], srcl);
            unsigned a1 = (unsigned)__shfl((int)pk[1][d & 1], srcl);
            un.u[d] = (g >> 1) ? a1 : a0;
        }
        return un.v;
    };

    bh8 kf0[4][2], kf1[4][2];
    f4 sA[4], sB[4];

    // prologue: V[0] staged, K[0]/K[1] in regs, S[0] computed
    stageV(0, 0);
    loadK(kf0, 0);
    loadK(kf1, 64);
    qkComp(sA, kf0);
    __syncthreads();

    // swizzled V byte-offset (h = k-half, ct = channel tile)
    auto voff = [&](int ct, int h) {
        return (16 * ct + li) * 128 + ((64 * h + 16 * g) ^ ((li & 7) << 4));
    };

    auto step = [&](int tt, bh8 (&kNext)[4][2], bh8 (&kLoad)[4][2],
                    f4 (&sCur)[4], f4 (&sNxt)[4], int buf) {
        const char* vsb = (const char*)vs[buf];

        // ---- G0 V prefetch (h=0, ct 0..7): hides under QK+softmax ----
        bh8 va[8], vb2[8];
#pragma unroll
        for (int ct = 0; ct < 8; ++ct) va[ct] = *(const bh8*)(vsb + voff(ct, 0));

        if (tt < 63) stageV(buf ^ 1, (tt + 1) << 6);
        if (tt < 62) loadK(kLoad, (tt + 2) << 6);

        // ---- QK for tile tt+1 (independent of sCur -> overlaps softmax) ----
        if (tt < 63) qkComp(sNxt, kNext);

        // ---- online softmax on sCur with defer-max (THR=8) ----
        float mx = sCur[0][0];
#pragma unroll
        for (int jt = 0; jt < 4; ++jt)
#pragma unroll
            for (int e = 0; e < 4; ++e) mx = fmaxf(mx, sCur[jt][e]);
        mx = fmaxf(mx, __shfl_xor(mx, 16));
        mx = fmaxf(mx, __shfl_xor(mx, 32));
        if (!__all(mx <= m + 8.f)) {
            float mnew = fmaxf(m, mx);
            float sc = __expf(m - mnew);
            l *= sc;
#pragma unroll
            for (int ct = 0; ct < 16; ++ct)
#pragma unroll
                for (int e = 0; e < 4; ++e) acc[ct][e] *= sc;
            m = mnew;
        }
        float sum = 0.f;
#pragma unroll
        for (int jt = 0; jt < 4; ++jt)
#pragma unroll
            for (int e = 0; e < 4; ++e) {
                float p = __expf(sCur[jt][e] - m);
                sCur[jt][e] = p;
                sum += p;
            }
        sum += __shfl_xor(sum, 16);
        sum += __shfl_xor(sum, 32);
        l += sum;

        // ---- P fragments for both k-halves ----
        bh8 pb0 = mkpb(sCur, 0);
        bh8 pb1 = mkpb(sCur, 1);

        // ---- PV in 4 groups of 8; each group's reads issued one group early
        __builtin_amdgcn_s_setprio(1);
#pragma unroll
        for (int ct = 0; ct < 8; ++ct) vb2[ct] = *(const bh8*)(vsb + voff(ct + 8, 0));  // G1
#pragma unroll
        for (int ct = 0; ct < 8; ++ct)
            acc[ct] = __builtin_amdgcn_mfma_f32_16x16x32_bf16(va[ct], pb0, acc[ct], 0, 0, 0);  // G0
#pragma unroll
        for (int ct = 0; ct < 8; ++ct) va[ct] = *(const bh8*)(vsb + voff(ct, 1));  // G2
#pragma unroll
        for (int ct = 0; ct < 8; ++ct)
            acc[ct + 8] = __builtin_amdgcn_mfma_f32_16x16x32_bf16(vb2[ct], pb0, acc[ct + 8], 0, 0, 0);  // G1
#pragma unroll
        for (int ct = 0; ct < 8; ++ct) vb2[ct] = *(const bh8*)(vsb + voff(ct + 8, 1));  // G3
#pragma unroll
        for (int ct = 0; ct < 8; ++ct)
            acc[ct] = __builtin_amdgcn_mfma_f32_16x16x32_bf16(va[ct], pb1, acc[ct], 0, 0, 0);  // G2
#pragma unroll
        for (int ct = 0; ct < 8; ++ct)
            acc[ct + 8] = __builtin_amdgcn_mfma_f32_16x16x32_bf16(vb2[ct], pb1, acc[ct + 8], 0, 0, 0);  // G3
        __builtin_amdgcn_s_setprio(0);
        __syncthreads();  // V[tt+1] staged (vmcnt drained), vs[buf] reads done
    };

    for (int tt = 0; tt < 64; tt += 2) {
        step(tt, kf1, kf0, sA, sB, 0);
        step(tt + 1, kf0, kf1, sB, sA, 1);
    }

    // ---- epilogue: out = gamma*(acc/l) + x ----
    float gm = gamma[0];
    float rl = 1.f / l;
    const float* xb = x + ((size_t)b * CC) * NN;
    float* ob = out + ((size_t)b * CC) * NN;
    int i = qb + li;
#pragma unroll
    for (int ct = 0; ct < 16; ++ct)
#pragma unroll
        for (int e = 0; e < 4; ++e) {
            int c = 16 * ct + 4 * g + e;
            size_t idx = (size_t)c * NN + i;
            ob[idx] = gm * (acc[ct][e] * rl) + xb[idx];
        }
}

// ---------------------------------------------------------------------------
extern "C" void kernel_launch(void* const* d_in, const int* in_sizes, int n_in,
                              void* d_out, int out_size, void* d_ws, size_t ws_size,
                              hipStream_t stream) {
    const float* x = (const float*)d_in[0];
    const float* Wq = (const float*)d_in[1];
    const float* bq = (const float*)d_in[2];
    const float* Wk = (const float*)d_in[3];
    const float* bk = (const float*)d_in[4];
    const float* Wv = (const float*)d_in[5];
    const float* bv = (const float*)d_in[6];
    const float* gamma = (const float*)d_in[7];
    float* out = (float*)d_out;

    // workspace layout (bytes):
    // q64 @0 (4MB) | k64 @4MB (4MB) | vC @8MB (16MB) | WcatT @24MB | bcat
    unsigned short* ws16 = (unsigned short*)d_ws;
    unsigned short* q64w = ws16;
    unsigned short* k64w = ws16 + 2097152;
    unsigned short* vCw = ws16 + 4194304;
    float* WcatT = (float*)((char*)d_ws + 25165824);
    float* bcat = WcatT + 81920;

    prep_w_kernel<<<320, 256, 0, stream>>>(Wq, bq, Wk, bk, Wv, bv, WcatT, bcat);
    qkv_kernel<<<BB * (NN / 64), 256, 0, stream>>>(x, WcatT, bcat, q64w, k64w, vCw);
    attn_kernel<<<512, 256, 0, stream>>>(q64w, k64w, vCw, x, gamma, out);
}

// Round 8
// 230.485 us; speedup vs baseline: 1.3713x; 1.3713x over previous
//
#include <hip/hip_runtime.h>
#include <math.h>

#define BB 8
#define CC 256
#define NN 4096

typedef float f4 __attribute__((ext_vector_type(4)));
typedef short bh8 __attribute__((ext_vector_type(8)));

__device__ __forceinline__ unsigned short f2bf(float f) {
    unsigned u = __builtin_bit_cast(unsigned, f);
    u += 0x7fff + ((u >> 16) & 1);
    return (unsigned short)(u >> 16);
}

// v_exp_f32 is natively 2^x — scores are pre-scaled by log2(e) in prep_w
__device__ __forceinline__ float exp2_fast(float x) {
    float r;
    asm("v_exp_f32 %0, %1" : "=v"(r) : "v"(x));
    return r;
}

// ---------------------------------------------------------------------------
// Kernel 0: concatenate weights into WcatT[c][320] + bcat[320] (fp32).
// q rows (o<32) pre-scaled by log2(e) so softmax uses raw v_exp_f32 (2^x).
// ---------------------------------------------------------------------------
__global__ void prep_w_kernel(const float* __restrict__ Wq, const float* __restrict__ bq,
                              const float* __restrict__ Wk, const float* __restrict__ bk,
                              const float* __restrict__ Wv, const float* __restrict__ bv,
                              float* __restrict__ WcatT, float* __restrict__ bcat) {
    const float L2E = 1.4426950408889634f;
    int idx = blockIdx.x * 256 + threadIdx.x;
    if (idx < 320) {
        bcat[idx] = (idx < 32) ? bq[idx] * L2E : (idx < 64 ? bk[idx - 32] : bv[idx - 64]);
    }
    if (idx < 320 * 256) {
        int o = idx >> 8;
        int c = idx & 255;
        float v = (o < 32) ? Wq[o * 256 + c] * L2E
                           : (o < 64 ? Wk[(o - 32) * 256 + c] : Wv[(o - 64) * 256 + c]);
        WcatT[c * 320 + o] = v;
    }
}

// ---------------------------------------------------------------------------
// Kernel 1: QKV projection (fp32 math), bf16 outputs. (R7 version, kept)
// ---------------------------------------------------------------------------
__global__ __launch_bounds__(256, 2) void qkv_kernel(
    const float* __restrict__ x, const float* __restrict__ WcatT,
    const float* __restrict__ bcat,
    unsigned short* __restrict__ q64, unsigned short* __restrict__ k64,
    unsigned short* __restrict__ vC) {
    __shared__ float xs[256 * 64];
    __shared__ unsigned short qkl[64 * 128];
    unsigned short* vsl = (unsigned short*)xs;  // [256][66] u16 overlay

    int blk = blockIdx.x;
    int b = blk >> 6;
    int i0 = (blk & 63) << 6;
    int t = threadIdx.x;

    const float* xb = x + ((size_t)b << 20);
    for (int idx = t; idx < 256 * 64; idx += 256) {
        int c = idx >> 6, ii = idx & 63;
        xs[idx] = xb[((size_t)c << 12) + i0 + ii];
    }
    __syncthreads();

    int to = t & 63;
    int tp = t >> 6;  // wave-uniform

    float acc[80];
#pragma unroll
    for (int uo = 0; uo < 5; ++uo) {
        float bias = bcat[to + 64 * uo];
#pragma unroll
        for (int pi = 0; pi < 16; ++pi) acc[uo * 16 + pi] = bias;
    }

    for (int c = 0; c < 256; ++c) {
        const float* wc = WcatT + c * 320 + to;
        float w0 = wc[0];
        float w1 = wc[64];
        float w2 = wc[128];
        float w3 = wc[192];
        float w4 = wc[256];
        const float4* xr = (const float4*)(xs + c * 64 + 16 * tp);
#pragma unroll
        for (int q = 0; q < 4; ++q) {
            float4 xv = xr[q];  // broadcast (wave-uniform address)
#pragma unroll
            for (int e = 0; e < 4; ++e) {
                int pi = 4 * q + e;
                float xe = (e == 0) ? xv.x : (e == 1) ? xv.y : (e == 2) ? xv.z : xv.w;
                acc[0 * 16 + pi] += w0 * xe;
                acc[1 * 16 + pi] += w1 * xe;
                acc[2 * 16 + pi] += w2 * xe;
                acc[3 * 16 + pi] += w3 * xe;
                acc[4 * 16 + pi] += w4 * xe;
            }
        }
    }
    __syncthreads();

#pragma unroll
    for (int pi = 0; pi < 16; ++pi) {
        int ii = 16 * tp + pi;
        float v = acc[pi];  // uo == 0
        unsigned short hi = f2bf(v);
        float vhi = __builtin_bit_cast(float, ((unsigned)hi) << 16);
        unsigned short lo = f2bf(v - vhi);
        if (to < 32) {
            qkl[ii * 128 + to] = hi;
            qkl[ii * 128 + 32 + to] = lo;
        } else {
            qkl[ii * 128 + 32 + to] = hi;
            qkl[ii * 128 + 64 + to] = lo;
        }
    }
#pragma unroll
    for (int uo = 1; uo < 5; ++uo) {
#pragma unroll
        for (int pi = 0; pi < 16; ++pi) {
            int c = to + 64 * (uo - 1);
            int ii = 16 * tp + pi;
            vsl[c * 66 + ii] = f2bf(acc[uo * 16 + pi]);
        }
    }
    __syncthreads();

    const unsigned* qk32 = (const unsigned*)qkl;
    unsigned* qb = (unsigned*)(q64 + ((size_t)(b * NN + i0)) * 64);
    unsigned* kb = (unsigned*)(k64 + ((size_t)(b * NN + i0)) * 64);
    for (int idx = t; idx < 64 * 32; idx += 256) {
        int row = idx >> 5, dw = idx & 31;
        qb[row * 32 + dw] = qk32[row * 64 + dw];
        kb[row * 32 + dw] = qk32[row * 64 + 32 + dw];
    }
    for (int idx = t; idx < 256 * 32; idx += 256) {
        int c = idx >> 5, dw = idx & 31;
        unsigned val = *(const unsigned*)(vsl + c * 66 + 2 * dw);
        *(unsigned*)(vC + ((size_t)(b * CC + c)) * NN + i0 + 2 * dw) = val;
    }
}

// ---------------------------------------------------------------------------
// Kernel 2: MFMA flash attention + residual. (R6 structure, verbatim, plus:
// exp2-domain softmax, precomputed staging base pointers.)
// Grid 512 (8 b x 64 q-tiles), 4 waves x 16 queries, 2 blocks/CU.
// Pipeline: QK[t+1] issued adjacent to softmax[t]; PV after. One barrier/step.
// Defer-max (THR = 8*log2e). V channel-major [256][64] bf16 LDS,
// XOR-swizzled, double-buffered via global_load_lds.
// ---------------------------------------------------------------------------
__global__ __launch_bounds__(256, 2) void attn_kernel(
    const unsigned short* __restrict__ q64, const unsigned short* __restrict__ k64,
    const unsigned short* __restrict__ vC, const float* __restrict__ x,
    const float* __restrict__ gamma, float* __restrict__ out) {
    __shared__ unsigned short vs[2][256 * 64];  // 64KB double-buffered V

    int t = threadIdx.x;
    int lane = t & 63;
    int w = t >> 6;
    int g = lane >> 4;
    int li = lane & 15;
    int blk = blockIdx.x;
    int b = blk & 7;            // XCD-affine batch mapping
    int i0 = (blk >> 3) << 6;   // 64-query tile
    int qb = i0 + 16 * w;       // wave's query base (16 queries)

    const unsigned short* vb = vC + ((size_t)b * CC) * NN;
    const unsigned short* kb = k64 + ((size_t)b * NN) * 64;

    // Q fragments (resident): [hi/lo]
    bh8 qf[2];
#pragma unroll
    for (int s = 0; s < 2; ++s)
        qf[s] = *(const bh8*)(q64 + ((size_t)(b * NN + qb + li)) * 64 + s * 32 + 8 * g);

    // loop-invariant staging base pointers (strength reduction)
    const unsigned short* vsrcb[8];
#pragma unroll
    for (int s = 0; s < 8; ++s) {
        int c = 64 * w + 8 * s + (lane >> 3);
        int slot = (lane & 7) ^ (c & 7);
        vsrcb[s] = vb + (size_t)c * NN + slot * 8;
    }
    const unsigned short* ksrcb[8];
#pragma unroll
    for (int jt = 0; jt < 4; ++jt)
#pragma unroll
        for (int s = 0; s < 2; ++s)
            ksrcb[jt * 2 + s] = kb + (size_t)(16 * jt + li) * 64 + s * 32 + 8 * g;

    f4 acc[16];
#pragma unroll
    for (int ct = 0; ct < 16; ++ct) acc[ct] = (f4){0.f, 0.f, 0.f, 0.f};
    float m = -INFINITY, l = 0.f;

    auto stageV = [&](int buf, int j0) {
#pragma unroll
        for (int s = 0; s < 8; ++s) {
            __builtin_amdgcn_global_load_lds(
                (const __attribute__((address_space(1))) unsigned int*)(vsrcb[s] + j0),
                (__attribute__((address_space(3))) unsigned int*)(&vs[buf][(64 * w + 8 * s) * 64]),
                16, 0, 0);
        }
    };
    auto loadK = [&](bh8 (&kf)[4][2], int j0) {
        size_t joff = (size_t)j0 * 64;
#pragma unroll
        for (int jt = 0; jt < 4; ++jt)
#pragma unroll
            for (int s = 0; s < 2; ++s)
                kf[jt][s] = *(const bh8*)(ksrcb[jt * 2 + s] + joff);
    };
    // QK^T (swapped, 3-product bf16 split => ~fp32 scores, log2e-scaled)
    auto qkComp = [&](f4 (&sOut)[4], bh8 (&kc)[4][2]) {
#pragma unroll
        for (int jt = 0; jt < 4; ++jt) {
            f4 a = {0.f, 0.f, 0.f, 0.f};
            a = __builtin_amdgcn_mfma_f32_16x16x32_bf16(kc[jt][0], qf[0], a, 0, 0, 0);
            a = __builtin_amdgcn_mfma_f32_16x16x32_bf16(kc[jt][1], qf[0], a, 0, 0, 0);
            a = __builtin_amdgcn_mfma_f32_16x16x32_bf16(kc[jt][0], qf[1], a, 0, 0, 0);
            sOut[jt] = a;
        }
    };
    // P^T fragment for k-half h via shfl redistribution (proven numerics)
    auto mkpb = [&](f4 (&sCur)[4], int h) -> bh8 {
        unsigned pk[2][2];
#pragma unroll
        for (int tl = 0; tl < 2; ++tl)
#pragma unroll
            for (int pp = 0; pp < 2; ++pp) {
                unsigned lo16 = f2bf(sCur[2 * h + tl][2 * pp]);
                unsigned hi16 = f2bf(sCur[2 * h + tl][2 * pp + 1]);
                pk[tl][pp] = lo16 | (hi16 << 16);
            }
        union { unsigned u[4]; bh8 v; } un;
#pragma unroll
        for (int d = 0; d < 4; ++d) {
            int srcl = (((2 * g + (d >> 1)) & 3) << 4) | li;
            unsigned a0 = (unsigned)__shfl((int)pk[0][d & 1], srcl);
            unsigned a1 = (unsigned)__shfl((int)pk[1][d & 1], srcl);
            un.u[d] = (g >> 1) ? a1 : a0;
        }
        return un.v;
    };

    bh8 kf0[4][2], kf1[4][2];
    f4 sA[4], sB[4];

    // prologue: V[0] staged, K[0]/K[1] in regs, S[0] computed
    stageV(0, 0);
    loadK(kf0, 0);
    loadK(kf1, 64);
    qkComp(sA, kf0);
    __syncthreads();

    auto step = [&](int tt, bh8 (&kNext)[4][2], bh8 (&kLoad)[4][2],
                    f4 (&sCur)[4], f4 (&sNxt)[4], int buf) {
        if (tt < 63) stageV(buf ^ 1, (tt + 1) << 6);
        if (tt < 62) loadK(kLoad, (tt + 2) << 6);

        // ---- QK for tile tt+1 (independent of sCur -> overlaps softmax) ----
        if (tt < 63) qkComp(sNxt, kNext);

        // ---- online softmax on sCur, exp2 domain, defer-max ----
        float mx = sCur[0][0];
#pragma unroll
        for (int jt = 0; jt < 4; ++jt)
#pragma unroll
            for (int e = 0; e < 4; ++e) mx = fmaxf(mx, sCur[jt][e]);
        mx = fmaxf(mx, __shfl_xor(mx, 16));
        mx = fmaxf(mx, __shfl_xor(mx, 32));
        if (!__all(mx <= m + 11.541561f)) {
            float mnew = fmaxf(m, mx);
            float sc = exp2_fast(m - mnew);
            l *= sc;
#pragma unroll
            for (int ct = 0; ct < 16; ++ct)
#pragma unroll
                for (int e = 0; e < 4; ++e) acc[ct][e] *= sc;
            m = mnew;
        }
        float sum = 0.f;
#pragma unroll
        for (int jt = 0; jt < 4; ++jt)
#pragma unroll
            for (int e = 0; e < 4; ++e) {
                float p = exp2_fast(sCur[jt][e] - m);
                sCur[jt][e] = p;
                sum += p;
            }
        sum += __shfl_xor(sum, 16);
        sum += __shfl_xor(sum, 32);
        l += sum;

        // ---- P^T fragments (in-register shfl redistribution) + PV ----
        const char* vsb = (const char*)vs[buf];
#pragma unroll
        for (int h = 0; h < 2; ++h) {
            bh8 pb = mkpb(sCur, h);
            __builtin_amdgcn_s_setprio(1);
#pragma unroll
            for (int ct = 0; ct < 16; ++ct) {
                int c = 16 * ct + li;
                int off = c * 128 + ((64 * h + 16 * g) ^ ((c & 7) << 4));
                bh8 vf = *(const bh8*)(vsb + off);
                acc[ct] = __builtin_amdgcn_mfma_f32_16x16x32_bf16(vf, pb, acc[ct], 0, 0, 0);
            }
            __builtin_amdgcn_s_setprio(0);
        }
        __syncthreads();  // V[tt+1] staged (vmcnt drained), vs[buf] reads done
    };

    for (int tt = 0; tt < 64; tt += 2) {
        step(tt, kf1, kf0, sA, sB, 0);
        step(tt + 1, kf0, kf1, sB, sA, 1);
    }

    // ---- epilogue: out = gamma*(acc/l) + x ----
    float gm = gamma[0];
    float rl = 1.f / l;
    const float* xb = x + ((size_t)b * CC) * NN;
    float* ob = out + ((size_t)b * CC) * NN;
    int i = qb + li;
#pragma unroll
    for (int ct = 0; ct < 16; ++ct)
#pragma unroll
        for (int e = 0; e < 4; ++e) {
            int c = 16 * ct + 4 * g + e;
            size_t idx = (size_t)c * NN + i;
            ob[idx] = gm * (acc[ct][e] * rl) + xb[idx];
        }
}

// ---------------------------------------------------------------------------
extern "C" void kernel_launch(void* const* d_in, const int* in_sizes, int n_in,
                              void* d_out, int out_size, void* d_ws, size_t ws_size,
                              hipStream_t stream) {
    const float* x = (const float*)d_in[0];
    const float* Wq = (const float*)d_in[1];
    const float* bq = (const float*)d_in[2];
    const float* Wk = (const float*)d_in[3];
    const float* bk = (const float*)d_in[4];
    const float* Wv = (const float*)d_in[5];
    const float* bv = (const float*)d_in[6];
    const float* gamma = (const float*)d_in[7];
    float* out = (float*)d_out;

    // workspace layout (bytes):
    // q64 @0 (4MB) | k64 @4MB (4MB) | vC @8MB (16MB) | WcatT @24MB | bcat
    unsigned short* ws16 = (unsigned short*)d_ws;
    unsigned short* q64w = ws16;
    unsigned short* k64w = ws16 + 2097152;
    unsigned short* vCw = ws16 + 4194304;
    float* WcatT = (float*)((char*)d_ws + 25165824);
    float* bcat = WcatT + 81920;

    prep_w_kernel<<<320, 256, 0, stream>>>(Wq, bq, Wk, bk, Wv, bv, WcatT, bcat);
    qkv_kernel<<<BB * (NN / 64), 256, 0, stream>>>(x, WcatT, bcat, q64w, k64w, vCw);
    attn_kernel<<<512, 256, 0, stream>>>(q64w, k64w, vCw, x, gamma, out);
}